// Round 7
// baseline (312.585 us; speedup 1.0000x reference)
//
#include <hip/hip_runtime.h>
#include <stdint.h>

#define T_TOK 4096
#define Hd    1024
#define Id    512
#define NE    16
#define NSLOT 32
#define TOPK  4
#define ECAP  1024
#define MAXT  (NE * (ECAP/128))

typedef __bf16 bf16x8 __attribute__((ext_vector_type(8)));
typedef float  floatx4 __attribute__((ext_vector_type(4)));

#define WAIT_VM(n) asm volatile("s_waitcnt vmcnt(" #n ")" ::: "memory")
#define CFENCE()   asm volatile("" ::: "memory")

static __device__ __forceinline__ void barrier_lgkm(){
  asm volatile("s_waitcnt lgkmcnt(0)\ns_barrier" ::: "memory");
}
static __device__ __forceinline__ void wg_barrier(){
  asm volatile("s_barrier" ::: "memory");
}

static __device__ __forceinline__ unsigned short f2bf(float f){
  unsigned int u = __float_as_uint(f);
  u = u + 0x7fffu + ((u >> 16) & 1u);
  return (unsigned short)(u >> 16);
}

static __device__ __forceinline__ void load_lds16(const void* g, void* l){
  __builtin_amdgcn_global_load_lds((const __attribute__((address_space(1))) void*)g,
                                   (__attribute__((address_space(3))) void*)l, 16, 0, 0);
}

// B-staging registers: 2 k-rows x 8 n of fp32 weights.
struct B8 { float4 a0, a1, b0, b1; };

static __device__ __forceinline__ B8 loadB(const float* p, int S){
  B8 r;
  r.a0 = *(const float4*)(p);
  r.a1 = *(const float4*)(p + 4);
  r.b0 = *(const float4*)(p + S);
  r.b1 = *(const float4*)(p + S + 4);
  return r;
}

// Pack fp32 pairs -> bf16 dwords (truncation; v_perm grabs high halves) and write
// LDS [n][40 shorts] (=20 dwords; 80B rows keep ds_read_b128 16B-aligned).
// low short = k even (row a), high short = k odd (row b).
static __device__ __forceinline__ void packB(const B8& r, uint32_t* dst, int ng8, int kq){
  dst[(ng8+0)*20 + kq] = __builtin_amdgcn_perm(__float_as_uint(r.b0.x), __float_as_uint(r.a0.x), 0x07060302u);
  dst[(ng8+1)*20 + kq] = __builtin_amdgcn_perm(__float_as_uint(r.b0.y), __float_as_uint(r.a0.y), 0x07060302u);
  dst[(ng8+2)*20 + kq] = __builtin_amdgcn_perm(__float_as_uint(r.b0.z), __float_as_uint(r.a0.z), 0x07060302u);
  dst[(ng8+3)*20 + kq] = __builtin_amdgcn_perm(__float_as_uint(r.b0.w), __float_as_uint(r.a0.w), 0x07060302u);
  dst[(ng8+4)*20 + kq] = __builtin_amdgcn_perm(__float_as_uint(r.b1.x), __float_as_uint(r.a1.x), 0x07060302u);
  dst[(ng8+5)*20 + kq] = __builtin_amdgcn_perm(__float_as_uint(r.b1.y), __float_as_uint(r.a1.y), 0x07060302u);
  dst[(ng8+6)*20 + kq] = __builtin_amdgcn_perm(__float_as_uint(r.b1.z), __float_as_uint(r.a1.z), 0x07060302u);
  dst[(ng8+7)*20 + kq] = __builtin_amdgcn_perm(__float_as_uint(r.b1.w), __float_as_uint(r.a1.w), 0x07060302u);
}

// ---------------- prep: x->bf16 + router logits (no weight work!) ----------------
// blocks [0,256): x cvt; [256,384): logits (+cursor zero)
__global__ __launch_bounds__(256) void prep_kernel(
    const float* __restrict__ x, const float* __restrict__ rw,
    unsigned short* __restrict__ xb, float* __restrict__ logits,
    int* __restrict__ cursors){
  __shared__ float srw[NSLOT*260];
  const int bid = blockIdx.x;
  const int tid = threadIdx.x;
  if (bid < 256){
    const int ib = bid * 4096;
    #pragma unroll
    for (int p = 0; p < 16; ++p){
      int i = ib + p*256 + tid;
      float4 v = ((const float4*)x)[i];
      ushort4 o;
      o.x = f2bf(v.x); o.y = f2bf(v.y); o.z = f2bf(v.z); o.w = f2bf(v.w);
      ((ushort4*)xb)[i] = o;
    }
  } else {
    const int lb = bid - 256;
    if (lb == 0 && tid < NE) cursors[tid] = 0;
    const int t  = lb * 32 + (tid >> 3);
    const int s0 = tid & 7;          // slots s0, s0+8, s0+16, s0+24: conflict-free banks
    float4 acc = {0.f, 0.f, 0.f, 0.f};
    for (int c = 0; c < 4; ++c){
      const int kc = c * 256;
      __syncthreads();
      #pragma unroll
      for (int p = 0; p < 8; ++p){
        int idx = tid + p*256;
        int s = idx >> 6;
        int col = (idx & 63) << 2;
        *(float4*)&srw[s*260 + col] = *(const float4*)(rw + (size_t)s*Hd + kc + col);
      }
      __syncthreads();
      for (int k = 0; k < 256; k += 4){
        float4 xv = *(const float4*)(x + (size_t)t*Hd + kc + k);
        float4 r0 = *(const float4*)&srw[(s0+ 0)*260 + k];
        float4 r1 = *(const float4*)&srw[(s0+ 8)*260 + k];
        float4 r2 = *(const float4*)&srw[(s0+16)*260 + k];
        float4 r3 = *(const float4*)&srw[(s0+24)*260 + k];
        acc.x += xv.x*r0.x + xv.y*r0.y + xv.z*r0.z + xv.w*r0.w;
        acc.y += xv.x*r1.x + xv.y*r1.y + xv.z*r1.z + xv.w*r1.w;
        acc.z += xv.x*r2.x + xv.y*r2.y + xv.z*r2.z + xv.w*r2.w;
        acc.w += xv.x*r3.x + xv.y*r3.y + xv.z*r3.z + xv.w*r3.w;
      }
    }
    logits[(size_t)t*NSLOT + s0     ] = acc.x;
    logits[(size_t)t*NSLOT + s0 +  8] = acc.y;
    logits[(size_t)t*NSLOT + s0 + 16] = acc.z;
    logits[(size_t)t*NSLOT + s0 + 24] = acc.w;
  }
}

// ---------------- softmax + bias + top-4 + direct row scatter + (out = zw*x) ----------------
__global__ __launch_bounds__(256) void topk_kernel(
    const float* __restrict__ logits, const float* __restrict__ bias,
    const float* __restrict__ x,
    int* __restrict__ cursors, int* __restrict__ rowmap, float* __restrict__ roww,
    float* __restrict__ out){
  __shared__ float szw[8];
  const int tid = threadIdx.x;
  if (tid < 8){
    const int t = blockIdx.x * 8 + tid;
    float sc[32], bsc[32];
    #pragma unroll
    for (int i = 0; i < 32; i += 4){
      float4 v = *(const float4*)(logits + (size_t)t*NSLOT + i);
      sc[i] = v.x; sc[i+1] = v.y; sc[i+2] = v.z; sc[i+3] = v.w;
    }
    float mx = sc[0];
    #pragma unroll
    for (int i = 1; i < 32; ++i) mx = fmaxf(mx, sc[i]);
    float sum = 0.f;
    #pragma unroll
    for (int i = 0; i < 32; ++i){ sc[i] = __expf(sc[i]-mx); sum += sc[i]; }
    float inv = 1.f / sum;
    #pragma unroll
    for (int i = 0; i < 32; ++i){ sc[i] *= inv; bsc[i] = sc[i] + bias[i]; }
    unsigned int chosen = 0;
    float zw = 0.f;
    #pragma unroll
    for (int k = 0; k < TOPK; ++k){
      float bv = -1e30f, bw = 0.f; int best = 0;
      #pragma unroll
      for (int i = 0; i < 32; ++i){
        float v = ((chosen >> i) & 1u) ? -1e30f : bsc[i];
        if (v > bv){ bv = v; best = i; bw = sc[i]; }
      }
      chosen |= (1u << best);
      if (best < NE){
        int pos = atomicAdd(&cursors[best], 1);
        rowmap[best*ECAP + pos] = t;
        roww[best*ECAP + pos]   = bw;
      } else zw += bw;
    }
    szw[tid] = zw;
  }
  __syncthreads();
  const int lane = tid & 63, wid = tid >> 6;
  const size_t base = (size_t)blockIdx.x * 8 * Hd;
  #pragma unroll
  for (int r0 = 0; r0 < 8; r0 += 4){
    int r = r0 + wid;
    float s = szw[r];
    const float4* xs = (const float4*)(x + base + (size_t)r*Hd);
    float4* os = (float4*)(out + base + (size_t)r*Hd);
    #pragma unroll
    for (int q = 0; q < 4; ++q){
      float4 v = xs[lane + q*64];
      float4 o; o.x = v.x*s; o.y = v.y*s; o.z = v.z*s; o.w = v.w*s;
      os[lane + q*64] = o;
    }
  }
}

// Map linear tile -> (expert, row-base e*ECAP, rows ne, m0). False if out of range.
static __device__ __forceinline__ bool tile_map(const int* __restrict__ counts, int tile,
                                                int& e, int& off, int& ne, int& m0){
  int cumT = 0; e = -1; ne = 0; m0 = 0;
  #pragma unroll
  for (int ee = 0; ee < NE; ++ee){
    int c = counts[ee];
    int nt = (c + 127) >> 7;
    bool here = (e < 0) && (tile < cumT + nt);
    if (here){ e = ee; ne = c; m0 = (tile - cumT) * 128; }
    cumT += nt;
  }
  off = (e >= 0) ? e * ECAP : 0;
  return e >= 0;
}

// ---------------- fused gate+up GEMM + SwiGLU; B staged from fp32 [k][n] ----------------
// (256,2): 128 AGPR acc + ~130 VGPR (B regs 32) ~ 2 waves/SIMD cap 256 -> fits.
// 3 waves/SIMD would spill (round-3 regression). Do not raise.
__global__ __launch_bounds__(256, 2) void gateup_kernel(
    const unsigned short* __restrict__ xb,
    const float* __restrict__ wg, const float* __restrict__ wu,
    const int* __restrict__ counts, const int* __restrict__ rowmap,
    const float* __restrict__ roww, unsigned short* __restrict__ act){
  const int b = blockIdx.x;
  int e, off, ne, m0;
  if (!tile_map(counts, b >> 2, e, off, ne, m0)) return;
  const int n0 = (b & 3) * 128;

  __shared__ unsigned short sA [2][128*32];   // A: [m][32k], glds path
  __shared__ unsigned short sBg[2][128*40];   // B: [n][40k-padded]
  __shared__ unsigned short sBu[2][128*40];
  __shared__ int sT[128];

  const int tid = threadIdx.x, lane = tid & 63, wid = tid >> 6;
  if (tid < 128){ int r = m0 + tid; sT[tid] = rowmap[off + ((r < ne) ? r : 0)]; }
  __syncthreads();

  const int r_in = lane >> 2, seg = lane & 3;
  const int rt0 = wid*32 + r_in, rt1 = rt0 + 16;
  const unsigned short* pA0 = xb + (size_t)sT[rt0]*Hd + seg*8;
  const unsigned short* pA1 = xb + (size_t)sT[rt1]*Hd + seg*8;
  const int dA0 = wid*1024, dA1 = wid*1024 + 512;

  const size_t wbase = (size_t)e * Hd * Id;
  const int ng8 = (tid >> 4) * 8;     // 8-n group
  const int kq  = tid & 15;           // k-pair index (k = 2*kq, 2*kq+1)
  const float* pG = wg + wbase + (size_t)(kq*2)*Id + n0 + ng8;
  const float* pU = wu + wbase + (size_t)(kq*2)*Id + n0 + ng8;

  floatx4 accg[4][4], accu[4][4];
  #pragma unroll
  for (int i = 0; i < 4; ++i)
    #pragma unroll
    for (int j = 0; j < 4; ++j){
      floatx4 z = {0.f,0.f,0.f,0.f};
      accg[i][j] = z; accu[i][j] = z;
    }
  const int wm = (wid & 1) * 64, wn = (wid >> 1) * 64;
  const int fm = lane & 15, fq = lane >> 4;

  // prologue: B0 regs -> pack buf0; A0 glds -> buf0; B1 regs in flight
  B8 rg = loadB(pG, Id);
  B8 ru = loadB(pU, Id);
  load_lds16(pA0, &sA[0][dA0]); load_lds16(pA1, &sA[0][dA1]);
  CFENCE();
  packB(rg, (uint32_t*)&sBg[0][0], ng8, kq);   // implicit vmcnt wait drains B0
  packB(ru, (uint32_t*)&sBu[0][0], ng8, kq);
  CFENCE();
  rg = loadB(pG + (size_t)32*Id, Id);
  ru = loadB(pU + (size_t)32*Id, Id);
  // vm queue: [A0 x2, B1 x8]

  for (int kit = 0; kit < 32; ++kit){
    const int cur = kit & 1;
    if (kit < 31){
      const int nb = 1 - cur;
      const int nk = (kit + 1) * 32;
      load_lds16(pA0 + nk, &sA[nb][dA0]);
      load_lds16(pA1 + nk, &sA[nb][dA1]);
      CFENCE();
      packB(rg, (uint32_t*)&sBg[nb][0], ng8, kq);  // waits B(kit+1) regs (drains older too)
      packB(ru, (uint32_t*)&sBu[nb][0], ng8, kq);
      CFENCE();
      const size_t k2 = (size_t)((kit < 30) ? (kit + 2) : 31) * 32;
      rg = loadB(pG + k2*Id, Id);
      ru = loadB(pU + k2*Id, Id);
      WAIT_VM(8);            // drain A(kit+1) glds; keep B(kit+2) x8 in flight
    }
    barrier_lgkm();          // ds_writes + glds visible to all
    bf16x8 av[4], bgv[4], buv[4];
    #pragma unroll
    for (int i = 0; i < 4; ++i)
      av[i] = *(const bf16x8*)(&sA[cur][(wm + i*16 + fm)*32 + fq*8]);
    #pragma unroll
    for (int j = 0; j < 4; ++j){
      bgv[j] = *(const bf16x8*)(&sBg[cur][(wn + j*16 + fm)*40 + fq*8]);
      buv[j] = *(const bf16x8*)(&sBu[cur][(wn + j*16 + fm)*40 + fq*8]);
    }
    #pragma unroll
    for (int i = 0; i < 4; ++i)
      #pragma unroll
      for (int j = 0; j < 4; ++j){
        accg[i][j] = __builtin_amdgcn_mfma_f32_16x16x32_bf16(av[i], bgv[j], accg[i][j], 0, 0, 0);
        accu[i][j] = __builtin_amdgcn_mfma_f32_16x16x32_bf16(av[i], buv[j], accu[i][j], 0, 0, 0);
      }
    wg_barrier();            // all reads of cur done before it becomes nb
  }

  #pragma unroll
  for (int i = 0; i < 4; ++i){
    #pragma unroll
    for (int r = 0; r < 4; ++r){
      int row = wm + i*16 + fq*4 + r;
      if (m0 + row < ne){
        float w = roww[off + m0 + row];
        size_t rb = (size_t)(off + m0 + row) * Id + n0;
        #pragma unroll
        for (int j = 0; j < 4; ++j){
          float g = accg[i][j][r];
          float u = accu[i][j][r];
          float a = (g / (1.f + __expf(-g))) * u * w;
          act[rb + wn + j*16 + fm] = f2bf(a);
        }
      }
    }
  }
}

// ---------------- down GEMM + atomic scatter; B staged from fp32 wd [i][h] ----------------
// (256,4): 64 AGPR acc + ~85 VGPR <= 128 cap -> no spill (verify VGPR_Count).
__global__ __launch_bounds__(256, 4) void down_kernel(
    const unsigned short* __restrict__ act,
    const float* __restrict__ wd,
    const int* __restrict__ counts, const int* __restrict__ rowmap,
    float* __restrict__ out){
  const int b = blockIdx.x;
  int e, off, ne, m0;
  if (!tile_map(counts, b >> 3, e, off, ne, m0)) return;
  const int n0 = (b & 7) * 128;

  __shared__ unsigned short sA[2][128*32];
  __shared__ unsigned short sB[2][128*40];
  __shared__ int sT[128];

  const int tid = threadIdx.x, lane = tid & 63, wid = tid >> 6;
  if (tid < 128){ int r = m0 + tid; sT[tid] = (r < ne) ? rowmap[off + r] : 0; }
  __syncthreads();

  const int r_in = lane >> 2, seg = lane & 3;
  const int rt0 = wid*32 + r_in, rt1 = rt0 + 16;
  const int gr0 = off + ((m0 + rt0 < ne) ? (m0 + rt0) : 0);
  const int gr1 = off + ((m0 + rt1 < ne) ? (m0 + rt1) : 0);
  const unsigned short* pA0 = act + (size_t)gr0*Id + seg*8;
  const unsigned short* pA1 = act + (size_t)gr1*Id + seg*8;
  const int dA0 = wid*1024, dA1 = wid*1024 + 512;

  const size_t wbase = (size_t)e * Id * Hd;
  const int ng8 = (tid >> 4) * 8;
  const int kq  = tid & 15;
  const float* pB = wd + wbase + (size_t)(kq*2)*Hd + n0 + ng8;

  floatx4 acc[4][4];
  #pragma unroll
  for (int i = 0; i < 4; ++i)
    #pragma unroll
    for (int j = 0; j < 4; ++j){ floatx4 z = {0.f,0.f,0.f,0.f}; acc[i][j] = z; }
  const int wm = (wid & 1) * 64, wn = (wid >> 1) * 64;
  const int fm = lane & 15, fq = lane >> 4;

  B8 rb = loadB(pB, Hd);
  load_lds16(pA0, &sA[0][dA0]); load_lds16(pA1, &sA[0][dA1]);
  CFENCE();
  packB(rb, (uint32_t*)&sB[0][0], ng8, kq);
  CFENCE();
  rb = loadB(pB + (size_t)32*Hd, Hd);
  // vm queue: [A0 x2, B1 x4]

  for (int kit = 0; kit < 16; ++kit){
    const int cur = kit & 1;
    if (kit < 15){
      const int nb = 1 - cur;
      const int nk = (kit + 1) * 32;
      load_lds16(pA0 + nk, &sA[nb][dA0]);
      load_lds16(pA1 + nk, &sA[nb][dA1]);
      CFENCE();
      packB(rb, (uint32_t*)&sB[nb][0], ng8, kq);
      CFENCE();
      const size_t k2 = (size_t)((kit < 14) ? (kit + 2) : 15) * 32;
      rb = loadB(pB + k2*Hd, Hd);
      WAIT_VM(4);            // drain A glds; keep B(kit+2) x4
    }
    barrier_lgkm();
    bf16x8 av[4], bv[4];
    #pragma unroll
    for (int i = 0; i < 4; ++i) av[i] = *(const bf16x8*)(&sA[cur][(wm + i*16 + fm)*32 + fq*8]);
    #pragma unroll
    for (int j = 0; j < 4; ++j) bv[j] = *(const bf16x8*)(&sB[cur][(wn + j*16 + fm)*40 + fq*8]);
    #pragma unroll
    for (int i = 0; i < 4; ++i)
      #pragma unroll
      for (int j = 0; j < 4; ++j)
        acc[i][j] = __builtin_amdgcn_mfma_f32_16x16x32_bf16(av[i], bv[j], acc[i][j], 0, 0, 0);
    wg_barrier();
  }

  #pragma unroll
  for (int i = 0; i < 4; ++i){
    #pragma unroll
    for (int r = 0; r < 4; ++r){
      int row = wm + i*16 + fq*4 + r;
      if (m0 + row < ne){
        int t = sT[row];
        #pragma unroll
        for (int j = 0; j < 4; ++j)
          atomicAdd(&out[(size_t)t*Hd + n0 + wn + j*16 + fm], acc[i][j][r]);
      }
    }
  }
}

// =================================================================
extern "C" void kernel_launch(void* const* d_in, const int* in_sizes, int n_in,
                              void* d_out, int out_size, void* d_ws, size_t ws_size,
                              hipStream_t stream){
  (void)in_sizes; (void)n_in; (void)out_size; (void)ws_size;
  const float* x    = (const float*)d_in[0];
  const float* rw   = (const float*)d_in[1];
  const float* bias = (const float*)d_in[2];
  const float* wg   = (const float*)d_in[3];
  const float* wu   = (const float*)d_in[4];
  const float* wd   = (const float*)d_in[5];
  float* out = (float*)d_out;

  char* ws = (char*)d_ws;
  unsigned short* xb  = (unsigned short*)ws;                       // 8.4 MB
  unsigned short* act = (unsigned short*)(ws + (size_t)T_TOK*Hd*2);// 16.8 MB
  char* misc = ws + (size_t)T_TOK*Hd*2 + (size_t)NE*ECAP*Id*2;

  const size_t LOGB = (size_t)T_TOK * NSLOT * 4;
  float* logits  = (float*)misc;
  int*   cursors = (int*)(misc + LOGB);
  char* p2 = misc + LOGB + 256;
  int*   rowmap = (int*)p2;                     p2 += (size_t)NE*ECAP*4;
  float* roww   = (float*)p2;

  prep_kernel<<<384, 256, 0, stream>>>(x, rw, xb, logits, cursors);
  topk_kernel<<<T_TOK/8, 256, 0, stream>>>(logits, bias, x, cursors, rowmap, roww, out);
  gateup_kernel<<<MAXT*4, 256, 0, stream>>>(xb, wg, wu, cursors, rowmap, roww, act);
  down_kernel<<<MAXT*8, 256, 0, stream>>>(act, wd, cursors, rowmap, out);
}

// Round 8
// 284.448 us; speedup vs baseline: 1.0989x; 1.0989x over previous
//
#include <hip/hip_runtime.h>
#include <stdint.h>

#define T_TOK 4096
#define Hd    1024
#define Id    512
#define NE    16
#define NSLOT 32
#define TOPK  4
#define ECAP  1024
#define MAXT  (NE * (ECAP/128))

typedef __bf16 bf16x8 __attribute__((ext_vector_type(8)));
typedef float  floatx4 __attribute__((ext_vector_type(4)));

#define WAIT_VM(n) asm volatile("s_waitcnt vmcnt(" #n ")" ::: "memory")

static __device__ __forceinline__ void wg_barrier(){
  asm volatile("" ::: "memory");
  __builtin_amdgcn_s_barrier();
  asm volatile("" ::: "memory");
}

static __device__ __forceinline__ unsigned short f2bf(float f){
  unsigned int u = __float_as_uint(f);
  u = u + 0x7fffu + ((u >> 16) & 1u);
  return (unsigned short)(u >> 16);
}

// bf16(hi_src) << 16 | bf16(lo_src), truncation rounding (hi halves via v_perm)
static __device__ __forceinline__ uint32_t bfpack(uint32_t hi_src, uint32_t lo_src){
  return __builtin_amdgcn_perm(hi_src, lo_src, 0x07060302u);
}

static __device__ __forceinline__ void load_lds16(const void* g, void* l){
  __builtin_amdgcn_global_load_lds((const __attribute__((address_space(1))) void*)g,
                                   (__attribute__((address_space(3))) void*)l, 16, 0, 0);
}

// ---------------- fused prep: logits + x->bf16 + register-transpose weights ----------------
// blocks [0,256): logits (long, scheduled first)  [256,512): x cvt
//        [512,6656): 64x64 transpose tiles, register-only (no LDS, no barriers)
__global__ __launch_bounds__(256) void prep_kernel(
    const float* __restrict__ wg, const float* __restrict__ wu,
    const float* __restrict__ wd, const float* __restrict__ x,
    const float* __restrict__ rw,
    unsigned short* __restrict__ wgb, unsigned short* __restrict__ wub,
    unsigned short* __restrict__ wdb, unsigned short* __restrict__ xb,
    float* __restrict__ logits, int* __restrict__ cursors){
  const int bid = blockIdx.x;
  const int tid = threadIdx.x;
  if (bid < 256){
    // ---- router logits, 16 tokens/block, 2 slots/thread ----
    __shared__ float srw[NSLOT*260];
    if (bid == 0 && tid < NE) cursors[tid] = 0;
    const int t  = bid * 16 + (tid >> 4);
    const int s0 = tid & 15;          // slots s0, s0+16
    float accx = 0.f, accy = 0.f;
    for (int c = 0; c < 4; ++c){
      const int kc = c * 256;
      __syncthreads();
      #pragma unroll
      for (int p = 0; p < 8; ++p){
        int idx = tid + p*256;
        int s = idx >> 6;
        int col = (idx & 63) << 2;
        *(float4*)&srw[s*260 + col] = *(const float4*)(rw + (size_t)s*Hd + kc + col);
      }
      __syncthreads();
      for (int k = 0; k < 256; k += 4){
        float4 xv = *(const float4*)(x + (size_t)t*Hd + kc + k);
        float4 r0 = *(const float4*)&srw[(s0     )*260 + k];
        float4 r1 = *(const float4*)&srw[(s0 + 16)*260 + k];
        accx += xv.x*r0.x + xv.y*r0.y + xv.z*r0.z + xv.w*r0.w;
        accy += xv.x*r1.x + xv.y*r1.y + xv.z*r1.z + xv.w*r1.w;
      }
    }
    logits[(size_t)t*NSLOT + s0     ] = accx;
    logits[(size_t)t*NSLOT + s0 + 16] = accy;
  } else if (bid < 512){
    // ---- x -> bf16 ----
    const int ib = (bid - 256) * 4096;
    #pragma unroll
    for (int p = 0; p < 16; ++p){
      int i = ib + p*256 + tid;
      float4 v = ((const float4*)x)[i];
      ushort4 o;
      o.x = f2bf(v.x); o.y = f2bf(v.y); o.z = f2bf(v.z); o.w = f2bf(v.w);
      ((ushort4*)xb)[i] = o;
    }
  } else {
    // ---- register-only 64x64 transpose-convert tile ----
    const int tb = bid - 512;                 // 0..6143
    const float* src; unsigned short* dst; int R, C, rt, ct;
    const int arr = tb >> 11;                 // 0:wg 1:wu 2:wd (2048 tiles each)
    const int rem = tb & 2047;
    const int e  = rem >> 7;                  // 128 tiles/expert
    const int t2 = rem & 127;
    if (arr == 0)      { src = wg; dst = wgb; R = Hd; C = Id; rt = t2 >> 3; ct = t2 & 7;  }
    else if (arr == 1) { src = wu; dst = wub; R = Hd; C = Id; rt = t2 >> 3; ct = t2 & 7;  }
    else               { src = wd; dst = wdb; R = Id; C = Hd; rt = t2 >> 4; ct = t2 & 15; }
    const int r0 = rt * 64, c0 = ct * 64;
    const float* s = src + (size_t)e * R * C;
    unsigned short* d = dst + (size_t)e * R * C;
    const int r_idx = tid >> 4;               // 16 r-blocks x 4 rows
    const int c_idx = tid & 15;               // 16 c-blocks x 4 cols
    const int rr = r0 + r_idx * 4;
    const int cc = c0 + c_idx * 4;
    uint4 u0 = *(const uint4*)(s + (size_t)(rr + 0)*C + cc);
    uint4 u1 = *(const uint4*)(s + (size_t)(rr + 1)*C + cc);
    uint4 u2 = *(const uint4*)(s + (size_t)(rr + 2)*C + cc);
    uint4 u3 = *(const uint4*)(s + (size_t)(rr + 3)*C + cc);
    uint2 o;
    o.x = bfpack(u1.x, u0.x); o.y = bfpack(u3.x, u2.x);
    *(uint2*)(d + (size_t)(cc + 0)*R + rr) = o;
    o.x = bfpack(u1.y, u0.y); o.y = bfpack(u3.y, u2.y);
    *(uint2*)(d + (size_t)(cc + 1)*R + rr) = o;
    o.x = bfpack(u1.z, u0.z); o.y = bfpack(u3.z, u2.z);
    *(uint2*)(d + (size_t)(cc + 2)*R + rr) = o;
    o.x = bfpack(u1.w, u0.w); o.y = bfpack(u3.w, u2.w);
    *(uint2*)(d + (size_t)(cc + 3)*R + rr) = o;
  }
}

// ---------------- softmax + bias + top-4 + direct row scatter + (out = zw*x) ----------------
__global__ __launch_bounds__(256) void topk_kernel(
    const float* __restrict__ logits, const float* __restrict__ bias,
    const float* __restrict__ x,
    int* __restrict__ cursors, int* __restrict__ rowmap, float* __restrict__ roww,
    float* __restrict__ out){
  __shared__ float szw[8];
  const int tid = threadIdx.x;
  if (tid < 8){
    const int t = blockIdx.x * 8 + tid;
    float sc[32], bsc[32];
    #pragma unroll
    for (int i = 0; i < 32; i += 4){
      float4 v = *(const float4*)(logits + (size_t)t*NSLOT + i);
      sc[i] = v.x; sc[i+1] = v.y; sc[i+2] = v.z; sc[i+3] = v.w;
    }
    float mx = sc[0];
    #pragma unroll
    for (int i = 1; i < 32; ++i) mx = fmaxf(mx, sc[i]);
    float sum = 0.f;
    #pragma unroll
    for (int i = 0; i < 32; ++i){ sc[i] = __expf(sc[i]-mx); sum += sc[i]; }
    float inv = 1.f / sum;
    #pragma unroll
    for (int i = 0; i < 32; ++i){ sc[i] *= inv; bsc[i] = sc[i] + bias[i]; }
    unsigned int chosen = 0;
    float zw = 0.f;
    #pragma unroll
    for (int k = 0; k < TOPK; ++k){
      float bv = -1e30f, bw = 0.f; int best = 0;
      #pragma unroll
      for (int i = 0; i < 32; ++i){
        float v = ((chosen >> i) & 1u) ? -1e30f : bsc[i];
        if (v > bv){ bv = v; best = i; bw = sc[i]; }
      }
      chosen |= (1u << best);
      if (best < NE){
        int pos = atomicAdd(&cursors[best], 1);
        rowmap[best*ECAP + pos] = t;
        roww[best*ECAP + pos]   = bw;
      } else zw += bw;
    }
    szw[tid] = zw;
  }
  __syncthreads();
  const int lane = tid & 63, wid = tid >> 6;
  const size_t base = (size_t)blockIdx.x * 8 * Hd;
  #pragma unroll
  for (int r0 = 0; r0 < 8; r0 += 4){
    int r = r0 + wid;
    float s = szw[r];
    const float4* xs = (const float4*)(x + base + (size_t)r*Hd);
    float4* os = (float4*)(out + base + (size_t)r*Hd);
    #pragma unroll
    for (int q = 0; q < 4; ++q){
      float4 v = xs[lane + q*64];
      float4 o; o.x = v.x*s; o.y = v.y*s; o.z = v.z*s; o.w = v.w*s;
      os[lane + q*64] = o;
    }
  }
}

// Map linear tile -> (expert, row-base e*ECAP, rows ne, m0). False if out of range.
static __device__ __forceinline__ bool tile_map(const int* __restrict__ counts, int tile,
                                                int& e, int& off, int& ne, int& m0){
  int cumT = 0; e = -1; ne = 0; m0 = 0;
  #pragma unroll
  for (int ee = 0; ee < NE; ++ee){
    int c = counts[ee];
    int nt = (c + 127) >> 7;
    bool here = (e < 0) && (tile < cumT + nt);
    if (here){ e = ee; ne = c; m0 = (tile - cumT) * 128; }
    cumT += nt;
  }
  off = (e >= 0) ? e * ECAP : 0;
  return e >= 0;
}

// ---------------- fused gate+up GEMM + SwiGLU (128x128, dbuf, glds) ----------------
// (256,2): 128 AGPR acc + ~90 VGPR ~ 220 regs/wave; 3 waves/SIMD cap=170 -> SPILLS
// (round-3 regression: WRITE_SIZE 243MB). Do not raise.
__global__ __launch_bounds__(256, 2) void gateup_kernel(
    const unsigned short* __restrict__ xb,
    const unsigned short* __restrict__ wgb,
    const unsigned short* __restrict__ wub,
    const int* __restrict__ counts,
    const int* __restrict__ rowmap,
    const float* __restrict__ roww,
    unsigned short* __restrict__ act){
  const int b = blockIdx.x;
  int e, off, ne, m0;
  if (!tile_map(counts, b >> 2, e, off, ne, m0)) return;
  const int n0 = (b & 3) * 128;

  __shared__ unsigned short sA [2][128*32];
  __shared__ unsigned short sBg[2][128*32];
  __shared__ unsigned short sBu[2][128*32];
  __shared__ int sT[128];

  const int tid = threadIdx.x, lane = tid & 63, wid = tid >> 6;
  if (tid < 128){ int r = m0 + tid; sT[tid] = rowmap[off + ((r < ne) ? r : 0)]; }
  __syncthreads();

  const int r_in = lane >> 2, seg = lane & 3;
  const int rt0 = wid*32 + r_in, rt1 = rt0 + 16;
  const size_t wbase = (size_t)e * Id * Hd;

  const unsigned short* pA0 = xb + (size_t)sT[rt0]*Hd + seg*8;
  const unsigned short* pA1 = xb + (size_t)sT[rt1]*Hd + seg*8;
  const unsigned short* pG0 = wgb + wbase + (size_t)(n0+rt0)*Hd + seg*8;
  const unsigned short* pG1 = wgb + wbase + (size_t)(n0+rt1)*Hd + seg*8;
  const unsigned short* pU0 = wub + wbase + (size_t)(n0+rt0)*Hd + seg*8;
  const unsigned short* pU1 = wub + wbase + (size_t)(n0+rt1)*Hd + seg*8;
  const int dA0 = wid*1024, dA1 = wid*1024 + 512;

  floatx4 accg[4][4], accu[4][4];
  #pragma unroll
  for (int i = 0; i < 4; ++i)
    #pragma unroll
    for (int j = 0; j < 4; ++j){
      floatx4 z = {0.f,0.f,0.f,0.f};
      accg[i][j] = z; accu[i][j] = z;
    }
  const int wm = (wid & 1) * 64, wn = (wid >> 1) * 64;
  const int fm = lane & 15, fq = lane >> 4;

  load_lds16(pA0, &sA[0][dA0]);  load_lds16(pA1, &sA[0][dA1]);
  load_lds16(pG0, &sBg[0][dA0]); load_lds16(pG1, &sBg[0][dA1]);
  load_lds16(pU0, &sBu[0][dA0]); load_lds16(pU1, &sBu[0][dA1]);

  #pragma unroll 2
  for (int kit = 0; kit < 32; ++kit){
    const int cur = kit & 1;
    if (kit < 31){
      const int nk = (kit+1)*32;
      const int nb = 1 - cur;
      load_lds16(pA0 + nk, &sA[nb][dA0]);  load_lds16(pA1 + nk, &sA[nb][dA1]);
      load_lds16(pG0 + nk, &sBg[nb][dA0]); load_lds16(pG1 + nk, &sBg[nb][dA1]);
      load_lds16(pU0 + nk, &sBu[nb][dA0]); load_lds16(pU1 + nk, &sBu[nb][dA1]);
      WAIT_VM(6);
    } else {
      WAIT_VM(0);
    }
    wg_barrier();
    bf16x8 av[4], bgv[4], buv[4];
    #pragma unroll
    for (int i = 0; i < 4; ++i)
      av[i] = *(const bf16x8*)(&sA[cur][(wm + i*16 + fm)*32 + fq*8]);
    #pragma unroll
    for (int j = 0; j < 4; ++j){
      bgv[j] = *(const bf16x8*)(&sBg[cur][(wn + j*16 + fm)*32 + fq*8]);
      buv[j] = *(const bf16x8*)(&sBu[cur][(wn + j*16 + fm)*32 + fq*8]);
    }
    #pragma unroll
    for (int i = 0; i < 4; ++i)
      #pragma unroll
      for (int j = 0; j < 4; ++j){
        accg[i][j] = __builtin_amdgcn_mfma_f32_16x16x32_bf16(av[i], bgv[j], accg[i][j], 0, 0, 0);
        accu[i][j] = __builtin_amdgcn_mfma_f32_16x16x32_bf16(av[i], buv[j], accu[i][j], 0, 0, 0);
      }
    wg_barrier();
  }

  #pragma unroll
  for (int i = 0; i < 4; ++i){
    #pragma unroll
    for (int r = 0; r < 4; ++r){
      int row = wm + i*16 + fq*4 + r;
      if (m0 + row < ne){
        float w = roww[off + m0 + row];
        size_t rb = (size_t)(off + m0 + row) * Id + n0;
        #pragma unroll
        for (int j = 0; j < 4; ++j){
          float g = accg[i][j][r];
          float u = accu[i][j][r];
          float a = (g / (1.f + __expf(-g))) * u * w;
          act[rb + wn + j*16 + fm] = f2bf(a);
        }
      }
    }
  }
}

// ---------------- down GEMM + atomic scatter (dbuf, glds) ----------------
// (256,4): 64 AGPR acc + ~60 VGPR = 124 <= 128 cap -> no spill.
__global__ __launch_bounds__(256, 4) void down_kernel(
    const unsigned short* __restrict__ act,
    const unsigned short* __restrict__ wdb,
    const int* __restrict__ counts,
    const int* __restrict__ rowmap,
    float* __restrict__ out){
  const int b = blockIdx.x;
  int e, off, ne, m0;
  if (!tile_map(counts, b >> 3, e, off, ne, m0)) return;
  const int n0 = (b & 7) * 128;

  __shared__ unsigned short sA[2][128*32];
  __shared__ unsigned short sB[2][128*32];
  __shared__ int sT[128];

  const int tid = threadIdx.x, lane = tid & 63, wid = tid >> 6;
  if (tid < 128){ int r = m0 + tid; sT[tid] = (r < ne) ? rowmap[off + r] : 0; }

  const int r_in = lane >> 2, seg = lane & 3;
  const int rt0 = wid*32 + r_in, rt1 = rt0 + 16;
  const int gr0 = off + ((m0 + rt0 < ne) ? (m0 + rt0) : 0);
  const int gr1 = off + ((m0 + rt1 < ne) ? (m0 + rt1) : 0);
  const size_t wbase = (size_t)e * Hd * Id;
  const unsigned short* pA0 = act + (size_t)gr0*Id + seg*8;
  const unsigned short* pA1 = act + (size_t)gr1*Id + seg*8;
  const unsigned short* pB0 = wdb + wbase + (size_t)(n0+rt0)*Id + seg*8;
  const unsigned short* pB1 = wdb + wbase + (size_t)(n0+rt1)*Id + seg*8;
  const int dA0 = wid*1024, dA1 = wid*1024 + 512;

  floatx4 acc[4][4];
  #pragma unroll
  for (int i = 0; i < 4; ++i)
    #pragma unroll
    for (int j = 0; j < 4; ++j){ floatx4 z = {0.f,0.f,0.f,0.f}; acc[i][j] = z; }
  const int wm = (wid & 1) * 64, wn = (wid >> 1) * 64;
  const int fm = lane & 15, fq = lane >> 4;

  load_lds16(pA0, &sA[0][dA0]); load_lds16(pA1, &sA[0][dA1]);
  load_lds16(pB0, &sB[0][dA0]); load_lds16(pB1, &sB[0][dA1]);

  #pragma unroll 2
  for (int kit = 0; kit < 16; ++kit){
    const int cur = kit & 1;
    if (kit < 15){
      const int nk = (kit+1)*32;
      const int nb = 1 - cur;
      load_lds16(pA0 + nk, &sA[nb][dA0]); load_lds16(pA1 + nk, &sA[nb][dA1]);
      load_lds16(pB0 + nk, &sB[nb][dA0]); load_lds16(pB1 + nk, &sB[nb][dA1]);
      WAIT_VM(4);
    } else {
      WAIT_VM(0);
    }
    wg_barrier();
    bf16x8 av[4], bv[4];
    #pragma unroll
    for (int i = 0; i < 4; ++i) av[i] = *(const bf16x8*)(&sA[cur][(wm + i*16 + fm)*32 + fq*8]);
    #pragma unroll
    for (int j = 0; j < 4; ++j) bv[j] = *(const bf16x8*)(&sB[cur][(wn + j*16 + fm)*32 + fq*8]);
    #pragma unroll
    for (int i = 0; i < 4; ++i)
      #pragma unroll
      for (int j = 0; j < 4; ++j)
        acc[i][j] = __builtin_amdgcn_mfma_f32_16x16x32_bf16(av[i], bv[j], acc[i][j], 0, 0, 0);
    wg_barrier();
  }

  #pragma unroll
  for (int i = 0; i < 4; ++i){
    #pragma unroll
    for (int r = 0; r < 4; ++r){
      int row = wm + i*16 + fq*4 + r;
      if (m0 + row < ne){
        int t = sT[row];
        #pragma unroll
        for (int j = 0; j < 4; ++j)
          atomicAdd(&out[(size_t)t*Hd + n0 + wn + j*16 + fm], acc[i][j][r]);
      }
    }
  }
}

// =================================================================
extern "C" void kernel_launch(void* const* d_in, const int* in_sizes, int n_in,
                              void* d_out, int out_size, void* d_ws, size_t ws_size,
                              hipStream_t stream){
  (void)in_sizes; (void)n_in; (void)out_size; (void)ws_size;
  const float* x    = (const float*)d_in[0];
  const float* rw   = (const float*)d_in[1];
  const float* bias = (const float*)d_in[2];
  const float* wg   = (const float*)d_in[3];
  const float* wu   = (const float*)d_in[4];
  const float* wd   = (const float*)d_in[5];
  float* out = (float*)d_out;

  char* ws = (char*)d_ws;
  const size_t WSZ = (size_t)NE * Id * Hd * 2;
  unsigned short* wgb = (unsigned short*)(ws);
  unsigned short* wub = (unsigned short*)(ws + WSZ);
  unsigned short* wdb = (unsigned short*)(ws + 2*WSZ);
  unsigned short* xb  = (unsigned short*)(ws + 3*WSZ);
  unsigned short* act = (unsigned short*)(ws + 3*WSZ + (size_t)T_TOK*Hd*2);
  char* misc = ws + 3*WSZ + (size_t)T_TOK*Hd*2 + (size_t)NE*ECAP*Id*2;

  const size_t LOGB = (size_t)T_TOK * NSLOT * 4;
  float* logits  = (float*)misc;
  int*   cursors = (int*)(misc + LOGB);
  char* p2 = misc + LOGB + 256;
  int*   rowmap = (int*)p2;                     p2 += (size_t)NE*ECAP*4;
  float* roww   = (float*)p2;

  prep_kernel<<<6656, 256, 0, stream>>>(wg, wu, wd, x, rw,
                                        wgb, wub, wdb, xb, logits, cursors);
  topk_kernel<<<T_TOK/8, 256, 0, stream>>>(logits, bias, x, cursors, rowmap, roww, out);
  gateup_kernel<<<MAXT*4, 256, 0, stream>>>(xb, wgb, wub, cursors, rowmap, roww, act);
  down_kernel<<<MAXT*8, 256, 0, stream>>>(act, wdb, cursors, rowmap, out);
}